// Round 10
// baseline (64.271 us; speedup 1.0000x reference)
//
#include <hip/hip_runtime.h>
#include <hip/hip_bf16.h>

// Fused bf16-MFMA: conv1d(64->64,k3,pad1)+relu -> conv1d(64->4,k3,pad1)+relu -> pixelshuffle(r=4)
// R10: persistent grid (1024 blocks = 4/CU resident), each block loops 4 consecutive
// t-tiles of one batch: { conv1 | bar | conv2 + stage(t+1) | bar }. stage(t+1) shares
// the conv2 phase (xs dead after conv1's barrier; hs disjoint) -> cross-tile overlap with
// zero cross-phase register state (R5/R6 spill trap avoided). conv1 unroll 3 for ILP.
// Keeps R9: 1 co-tile/wave conv1 (24-VGPR weights resident), float2 staging + interior
// fast path, XCD-bijective swizzle, pk2 pack, bias via MFMA C-in, XOR swizzle (row&7)<<4.

#define CC 64
#define LL 16384
#define NBATCH 32
#define TL 128
#define NTILE 128     // LL/TL
#define TPB 4         // tiles per block
#define XROWS 146     // x pos range [t*TL-2, t*TL+143]
#define PITCH 128     // bytes per LDS row (64 bf16)

typedef short short8 __attribute__((ext_vector_type(8)));
typedef float f32x4 __attribute__((ext_vector_type(4)));

__device__ __forceinline__ unsigned pk2(float a, float b) {
    unsigned short lo = __builtin_bit_cast(unsigned short, __float2bfloat16(a));
    unsigned short hi = __builtin_bit_cast(unsigned short, __float2bfloat16(b));
    return (unsigned)lo | ((unsigned)hi << 16);
}

// ---- weight repack: w1[64][64][3] f32 -> wp[k][co][ci] bf16 (12288)
//      w2[4][64][3]  f32 -> wp+12288 [k][oc16][ci] bf16 (3072), oc>=4 zero
__global__ void repack_weights(const float* __restrict__ w1,
                               const float* __restrict__ w2,
                               unsigned short* __restrict__ wp) {
    int i = blockIdx.x * 256 + threadIdx.x;
    if (i < 12288) {
        int kk = i >> 12;
        int rem = i & 4095;
        int co = rem >> 6;
        int ci = rem & 63;
        wp[i] = __builtin_bit_cast(unsigned short, __float2bfloat16(w1[(co * 64 + ci) * 3 + kk]));
    }
    if (i < 3072) {
        int kk = i >> 10;
        int rem = i & 1023;
        int oc = rem >> 6;
        int ci = rem & 63;
        float v = (oc < 4) ? w2[(oc * 64 + ci) * 3 + kk] : 0.0f;
        wp[12288 + i] = __builtin_bit_cast(unsigned short, __float2bfloat16(v));
    }
}

__global__ __launch_bounds__(256, 4)
void fused_upsample_mfma(const float* __restrict__ x,
                         const float* __restrict__ b1,
                         const float* __restrict__ b2,
                         const unsigned short* __restrict__ wp,
                         float* __restrict__ out) {
    __shared__ __align__(16) char lds[(XROWS + 2 + 144) * PITCH];
    char* const xs = lds;                         // rows 0..145 : x pos t*TL-2+row
    char* const hs = lds + (XROWS + 2) * PITCH;   // rows 0..143 : h pos t*TL-1+row

    // 1024 blocks: xcd = bid&7 owns batches 4*xcd..4*xcd+3; 32 tile-groups of 4 tiles
    const int bid = blockIdx.x;
    const int xcd = bid & 7;
    const int idx = bid >> 3;          // 0..127
    const int bb  = xcd * 4 + (idx >> 5);
    const int tg  = idx & 31;
    const int tbase = tg * TPB;        // tiles tbase..tbase+3

    const int tid  = threadIdx.x;
    const int lane = tid & 63;
    const int wave = tid >> 6;
    const int lr   = lane & 15;   // fragment row/col index
    const int lg   = lane >> 4;   // k-chunk group 0..3

    // staging geometry
    const int sc  = tid & 15;          // row-pair group: rows {it*32+2sc, +1}
    const int scg = tid >> 4;          // ci-group 0..15
    const long base0 = (long)(bb * CC + scg * 4) * LL;

    auto stage = [&](int t) {
        const int g0 = t * TL - 2;
        const bool interior = (t > 0) && (t < NTILE - 1);
        if (interior) {
            #pragma unroll
            for (int it = 0; it < 5; ++it) {
                int r = it * 32 + sc * 2;
                if (it < 4 || r < XROWS) {
                    float2 v0 = *(const float2*)(x + base0 + g0 + r);
                    float2 v1 = *(const float2*)(x + base0 + LL + g0 + r);
                    float2 v2 = *(const float2*)(x + base0 + 2 * LL + g0 + r);
                    float2 v3 = *(const float2*)(x + base0 + 3 * LL + g0 + r);
                    int byteA = (r * PITCH + scg * 8) ^ ((r & 7) << 4);
                    int byteB = ((r + 1) * PITCH + scg * 8) ^ (((r + 1) & 7) << 4);
                    *(uint2*)(xs + byteA) = make_uint2(pk2(v0.x, v1.x), pk2(v2.x, v3.x));
                    *(uint2*)(xs + byteB) = make_uint2(pk2(v0.y, v1.y), pk2(v2.y, v3.y));
                }
            }
        } else {
            #pragma unroll
            for (int it = 0; it < 5; ++it) {
                int r = it * 32 + sc * 2;
                if (it < 4 || r < XROWS) {
                    int ga = g0 + r, gb = g0 + r + 1;
                    bool oa = (unsigned)ga < (unsigned)LL;
                    bool ob = (unsigned)gb < (unsigned)LL;
                    float2 v[4];
                    #pragma unroll
                    for (int u = 0; u < 4; ++u) {
                        v[u].x = oa ? x[base0 + (long)u * LL + ga] : 0.f;
                        v[u].y = ob ? x[base0 + (long)u * LL + gb] : 0.f;
                    }
                    int byteA = (r * PITCH + scg * 8) ^ ((r & 7) << 4);
                    int byteB = ((r + 1) * PITCH + scg * 8) ^ (((r + 1) & 7) << 4);
                    *(uint2*)(xs + byteA) = make_uint2(pk2(v[0].x, v[1].x), pk2(v[2].x, v[3].x));
                    *(uint2*)(xs + byteB) = make_uint2(pk2(v[0].y, v[1].y), pk2(v[2].y, v[3].y));
                }
            }
        }
    };

    // ---- prologue: stage first tile ----
    stage(tbase);
    __syncthreads();

    for (int jj = 0; jj < TPB; ++jj) {
        const int t = tbase + jj;

        // ---------------- conv1: wave owns co-tile `wave`, loops all 9 pos-tiles ----------------
        {
            short8 A1[3][2];
            #pragma unroll
            for (int k = 0; k < 3; ++k)
                #pragma unroll
                for (int kc = 0; kc < 2; ++kc)
                    A1[k][kc] = *(const short8*)(wp + ((k * 64 + wave * 16 + lr) * 64 + kc * 32 + lg * 8));
            const f32x4 bias1 = *(const f32x4*)(b1 + wave * 16 + lg * 4);

            #pragma unroll 3
            for (int i = 0; i < 9; ++i) {
                f32x4 acc = bias1;
                #pragma unroll
                for (int k = 0; k < 3; ++k) {
                    int row = 16 * i + lr + k;             // xs row = p + k + 1
                    #pragma unroll
                    for (int kc = 0; kc < 2; ++kc) {
                        int byte = (row * PITCH + kc * 64 + lg * 16) ^ ((row & 7) << 4);
                        short8 Bf = *(const short8*)(xs + byte);
                        acc = __builtin_amdgcn_mfma_f32_16x16x32_bf16(A1[k][kc], Bf, acc, 0, 0, 0);
                    }
                }
                int p  = 16 * i - 1 + lr;                  // local h pos
                int hp = t * TL + p;                       // global h pos
                bool inr = (unsigned)hp < (unsigned)LL;
                float r0 = inr ? fmaxf(acc[0], 0.f) : 0.f;
                float r1 = inr ? fmaxf(acc[1], 0.f) : 0.f;
                float r2 = inr ? fmaxf(acc[2], 0.f) : 0.f;
                float r3 = inr ? fmaxf(acc[3], 0.f) : 0.f;
                int hrow = 16 * i + lr;                    // hs row = p + 1
                int byte = (hrow * PITCH + wave * 32 + lg * 8) ^ ((hrow & 7) << 4);
                *(uint2*)(hs + byte) = make_uint2(pk2(r0, r1), pk2(r2, r3));
            }
        }
        __syncthreads();

        // ---------------- conv2 + pixelshuffle store; then stage(t+1) (xs is free) ----------------
        {
            short8 A2[3][2];
            #pragma unroll
            for (int k = 0; k < 3; ++k)
                #pragma unroll
                for (int kc = 0; kc < 2; ++kc)
                    A2[k][kc] = *(const short8*)(wp + 12288 + ((k * 16 + lr) * 64 + kc * 32 + lg * 8));
            const f32x4 bias2v = *(const f32x4*)(b2);
            const f32x4 zero4 = {0.f, 0.f, 0.f, 0.f};
            const f32x4 acc2init = (lg == 0) ? bias2v : zero4;

            #pragma unroll
            for (int s = 0; s < 2; ++s) {
                int p0 = 16 * (wave * 2 + s);
                f32x4 acc = acc2init;
                #pragma unroll
                for (int k = 0; k < 3; ++k) {
                    int row = p0 + lr + k;                 // hs row = p + k
                    #pragma unroll
                    for (int kc = 0; kc < 2; ++kc) {
                        int byte = (row * PITCH + kc * 64 + lg * 16) ^ ((row & 7) << 4);
                        short8 Bf = *(const short8*)(hs + byte);
                        acc = __builtin_amdgcn_mfma_f32_16x16x32_bf16(A2[k][kc], Bf, acc, 0, 0, 0);
                    }
                }
                if (lane < 16) {                           // lg=0: regs 0..3 = oc 0..3
                    f32x4 o;
                    o[0] = fmaxf(acc[0], 0.f);
                    o[1] = fmaxf(acc[1], 0.f);
                    o[2] = fmaxf(acc[2], 0.f);
                    o[3] = fmaxf(acc[3], 0.f);
                    *(f32x4*)(out + (long)bb * (LL * 4) + (t * TL + p0 + lane) * 4) = o;
                }
            }
        }
        if (jj + 1 < TPB) stage(t + 1);
        __syncthreads();
    }
}

extern "C" void kernel_launch(void* const* d_in, const int* in_sizes, int n_in,
                              void* d_out, int out_size, void* d_ws, size_t ws_size,
                              hipStream_t stream) {
    const float* x  = (const float*)d_in[0];
    const float* w1 = (const float*)d_in[1];
    const float* b1 = (const float*)d_in[2];
    const float* w2 = (const float*)d_in[3];
    const float* b2 = (const float*)d_in[4];
    float* out = (float*)d_out;
    unsigned short* wp = (unsigned short*)d_ws;

    repack_weights<<<48, 256, 0, stream>>>(w1, w2, wp);
    fused_upsample_mfma<<<(NTILE / TPB) * NBATCH, 256, 0, stream>>>(x, b1, b2, wp, out);
}

// Round 11
// 61.666 us; speedup vs baseline: 1.0423x; 1.0423x over previous
//
#include <hip/hip_runtime.h>
#include <hip/hip_bf16.h>

// Fused bf16-MFMA: conv1d(64->64,k3,pad1)+relu -> conv1d(64->4,k3,pad1)+relu -> pixelshuffle(r=4)
// R11: R9 skeleton (best: 51.5us) + conv1 2-co-tile/wave split (halves conv1 LDS reads
// 216->108 b128/block) + amdgpu_waves_per_eu(4,4) occupancy pin so the allocator keeps
// the 48-VGPR weight set resident (R7's identical split failed at VGPR=52: compiler
// targeted 8 waves/EU and demoted weights to per-use reloads; LDS caps us at 4/EU anyway).
// Keeps R9: float2 staging + interior fast path, XCD-bijective swizzle, pk2 pack,
// bias via MFMA C-in, XOR swizzle (row&7)<<4.

#define CC 64
#define LL 16384
#define NBATCH 32
#define TL 128
#define NTILE 128     // LL/TL
#define XROWS 146     // x pos range [t*TL-2, t*TL+143]
#define PITCH 128     // bytes per LDS row (64 bf16)

typedef short short8 __attribute__((ext_vector_type(8)));
typedef float f32x4 __attribute__((ext_vector_type(4)));

__device__ __forceinline__ unsigned pk2(float a, float b) {
    unsigned short lo = __builtin_bit_cast(unsigned short, __float2bfloat16(a));
    unsigned short hi = __builtin_bit_cast(unsigned short, __float2bfloat16(b));
    return (unsigned)lo | ((unsigned)hi << 16);
}

// ---- weight repack: w1[64][64][3] f32 -> wp[k][co][ci] bf16 (12288)
//      w2[4][64][3]  f32 -> wp+12288 [k][oc16][ci] bf16 (3072), oc>=4 zero
__global__ void repack_weights(const float* __restrict__ w1,
                               const float* __restrict__ w2,
                               unsigned short* __restrict__ wp) {
    int i = blockIdx.x * 256 + threadIdx.x;
    if (i < 12288) {
        int kk = i >> 12;
        int rem = i & 4095;
        int co = rem >> 6;
        int ci = rem & 63;
        wp[i] = __builtin_bit_cast(unsigned short, __float2bfloat16(w1[(co * 64 + ci) * 3 + kk]));
    }
    if (i < 3072) {
        int kk = i >> 10;
        int rem = i & 1023;
        int oc = rem >> 6;
        int ci = rem & 63;
        float v = (oc < 4) ? w2[(oc * 64 + ci) * 3 + kk] : 0.0f;
        wp[12288 + i] = __builtin_bit_cast(unsigned short, __float2bfloat16(v));
    }
}

__global__ __launch_bounds__(256)
__attribute__((amdgpu_waves_per_eu(4, 4)))
void fused_upsample_mfma(const float* __restrict__ x,
                         const float* __restrict__ b1,
                         const float* __restrict__ b2,
                         const unsigned short* __restrict__ wp,
                         float* __restrict__ out) {
    __shared__ __align__(16) char lds[(XROWS + 2 + 144) * PITCH];
    char* const xs = lds;                         // rows 0..145 : x pos t*TL-2+row
    char* const hs = lds + (XROWS + 2) * PITCH;   // rows 0..143 : h pos t*TL-1+row

    // bijective XCD swizzle: 4096 blocks = 8 XCDs x 512; XCD k gets batches 4k..4k+3
    const int bid = blockIdx.x;
    const int swz = (bid & 7) * 512 + (bid >> 3);
    const int t   = swz & (NTILE - 1);
    const int bb  = swz >> 7;

    const int tid  = threadIdx.x;
    const int lane = tid & 63;
    const int wave = tid >> 6;
    const int lr   = lane & 15;   // fragment row/col index
    const int lg   = lane >> 4;   // k-chunk group 0..3
    const int c2   = wave & 1;    // conv1 co-half: co-tiles {2*c2, 2*c2+1}
    const int ph   = wave >> 1;   // conv1 pos-half: i in [ph*5, min(ph*5+5,9))

    // ---------------- stage x -> xs (float2 loads, interior fast path) ----------------
    {
        const int sc  = tid & 15;          // row-pair group: rows {it*32+2sc, +1}
        const int scg = tid >> 4;          // ci-group 0..15
        const long base0 = (long)(bb * CC + scg * 4) * LL;
        const int g0 = t * TL - 2;
        const bool interior = (t > 0) && (t < NTILE - 1);

        if (interior) {
            #pragma unroll
            for (int it = 0; it < 5; ++it) {
                int r = it * 32 + sc * 2;
                if (it < 4 || r < XROWS) {
                    float2 v0 = *(const float2*)(x + base0 + g0 + r);
                    float2 v1 = *(const float2*)(x + base0 + LL + g0 + r);
                    float2 v2 = *(const float2*)(x + base0 + 2 * LL + g0 + r);
                    float2 v3 = *(const float2*)(x + base0 + 3 * LL + g0 + r);
                    int byteA = (r * PITCH + scg * 8) ^ ((r & 7) << 4);
                    int byteB = ((r + 1) * PITCH + scg * 8) ^ (((r + 1) & 7) << 4);
                    *(uint2*)(xs + byteA) = make_uint2(pk2(v0.x, v1.x), pk2(v2.x, v3.x));
                    *(uint2*)(xs + byteB) = make_uint2(pk2(v0.y, v1.y), pk2(v2.y, v3.y));
                }
            }
        } else {
            #pragma unroll
            for (int it = 0; it < 5; ++it) {
                int r = it * 32 + sc * 2;
                if (it < 4 || r < XROWS) {
                    int ga = g0 + r, gb = g0 + r + 1;
                    bool oa = (unsigned)ga < (unsigned)LL;
                    bool ob = (unsigned)gb < (unsigned)LL;
                    float2 v[4];
                    #pragma unroll
                    for (int u = 0; u < 4; ++u) {
                        v[u].x = oa ? x[base0 + (long)u * LL + ga] : 0.f;
                        v[u].y = ob ? x[base0 + (long)u * LL + gb] : 0.f;
                    }
                    int byteA = (r * PITCH + scg * 8) ^ ((r & 7) << 4);
                    int byteB = ((r + 1) * PITCH + scg * 8) ^ (((r + 1) & 7) << 4);
                    *(uint2*)(xs + byteA) = make_uint2(pk2(v[0].x, v[1].x), pk2(v[2].x, v[3].x));
                    *(uint2*)(xs + byteB) = make_uint2(pk2(v[0].y, v[1].y), pk2(v[2].y, v[3].y));
                }
            }
        }
    }
    __syncthreads();

    // ---------------- conv1: wave = co-half c2 (2 co-tiles), pos-half ph ----------------
    {
        short8 A1[2][3][2];
        f32x4 bias1[2];
        #pragma unroll
        for (int u = 0; u < 2; ++u) {
            #pragma unroll
            for (int k = 0; k < 3; ++k)
                #pragma unroll
                for (int kc = 0; kc < 2; ++kc)
                    A1[u][k][kc] = *(const short8*)(wp + ((k * 64 + (c2 * 2 + u) * 16 + lr) * 64 + kc * 32 + lg * 8));
            bias1[u] = *(const f32x4*)(b1 + (c2 * 2 + u) * 16 + lg * 4);
        }

        #pragma unroll
        for (int ii = 0; ii < 5; ++ii) {
            int i = ph * 5 + ii;
            if (i < 9) {
                f32x4 acc0 = bias1[0];
                f32x4 acc1 = bias1[1];
                #pragma unroll
                for (int k = 0; k < 3; ++k) {
                    int row = 16 * i + lr + k;             // xs row = p + k + 1
                    #pragma unroll
                    for (int kc = 0; kc < 2; ++kc) {
                        int byte = (row * PITCH + kc * 64 + lg * 16) ^ ((row & 7) << 4);
                        short8 Bf = *(const short8*)(xs + byte);
                        acc0 = __builtin_amdgcn_mfma_f32_16x16x32_bf16(A1[0][k][kc], Bf, acc0, 0, 0, 0);
                        acc1 = __builtin_amdgcn_mfma_f32_16x16x32_bf16(A1[1][k][kc], Bf, acc1, 0, 0, 0);
                    }
                }
                int p  = 16 * i - 1 + lr;                  // local h pos
                int hp = t * TL + p;                       // global h pos
                bool inr = (unsigned)hp < (unsigned)LL;
                int hrow = 16 * i + lr;                    // hs row = p + 1
                #pragma unroll
                for (int u = 0; u < 2; ++u) {
                    f32x4 a = u ? acc1 : acc0;
                    float r0 = inr ? fmaxf(a[0], 0.f) : 0.f;
                    float r1 = inr ? fmaxf(a[1], 0.f) : 0.f;
                    float r2 = inr ? fmaxf(a[2], 0.f) : 0.f;
                    float r3 = inr ? fmaxf(a[3], 0.f) : 0.f;
                    int byte = (hrow * PITCH + (c2 * 2 + u) * 32 + lg * 8) ^ ((hrow & 7) << 4);
                    *(uint2*)(hs + byte) = make_uint2(pk2(r0, r1), pk2(r2, r3));
                }
            }
        }
    }
    __syncthreads();

    // ---------------- conv2 + pixelshuffle store: wave does 2 pos-tiles ----------------
    {
        short8 A2[3][2];
        #pragma unroll
        for (int k = 0; k < 3; ++k)
            #pragma unroll
            for (int kc = 0; kc < 2; ++kc)
                A2[k][kc] = *(const short8*)(wp + 12288 + ((k * 16 + lr) * 64 + kc * 32 + lg * 8));
        const f32x4 bias2v = *(const f32x4*)(b2);
        const f32x4 zero4 = {0.f, 0.f, 0.f, 0.f};
        const f32x4 acc2init = (lg == 0) ? bias2v : zero4;

        #pragma unroll
        for (int s = 0; s < 2; ++s) {
            int p0 = 16 * (wave * 2 + s);
            f32x4 acc = acc2init;
            #pragma unroll
            for (int k = 0; k < 3; ++k) {
                int row = p0 + lr + k;                 // hs row = p + k
                #pragma unroll
                for (int kc = 0; kc < 2; ++kc) {
                    int byte = (row * PITCH + kc * 64 + lg * 16) ^ ((row & 7) << 4);
                    short8 Bf = *(const short8*)(hs + byte);
                    acc = __builtin_amdgcn_mfma_f32_16x16x32_bf16(A2[k][kc], Bf, acc, 0, 0, 0);
                }
            }
            if (lane < 16) {                           // lg=0: regs 0..3 = oc 0..3
                f32x4 o;
                o[0] = fmaxf(acc[0], 0.f);
                o[1] = fmaxf(acc[1], 0.f);
                o[2] = fmaxf(acc[2], 0.f);
                o[3] = fmaxf(acc[3], 0.f);
                *(f32x4*)(out + (long)bb * (LL * 4) + (t * TL + p0 + lane) * 4) = o;
            }
        }
    }
}

extern "C" void kernel_launch(void* const* d_in, const int* in_sizes, int n_in,
                              void* d_out, int out_size, void* d_ws, size_t ws_size,
                              hipStream_t stream) {
    const float* x  = (const float*)d_in[0];
    const float* w1 = (const float*)d_in[1];
    const float* b1 = (const float*)d_in[2];
    const float* w2 = (const float*)d_in[3];
    const float* b2 = (const float*)d_in[4];
    float* out = (float*)d_out;
    unsigned short* wp = (unsigned short*)d_ws;

    repack_weights<<<48, 256, 0, stream>>>(w1, w2, wp);
    fused_upsample_mfma<<<NTILE * NBATCH, 256, 0, stream>>>(x, b1, b2, wp, out);
}

// Round 12
// 51.403 us; speedup vs baseline: 1.2503x; 1.1997x over previous
//
#include <hip/hip_runtime.h>
#include <hip/hip_bf16.h>

// Fused bf16-MFMA: conv1d(64->64,k3,pad1)+relu -> conv1d(64->4,k3,pad1)+relu -> pixelshuffle(r=4)
// R12: R9 skeleton (best: 51.5us) with ONE change: conv1 loop unroll 3 (cross-iteration
// ILP: 18 independent ds_reads + 18 MFMAs per group; epilogue of tile i overlaps reads
// of i+1). R10 bundled this with persistent-grid changes that spilled; isolated here.
// Keeps R9: 1 co-tile/wave conv1 (24-VGPR weights resident — R7/R8/R11 proved larger
// weight sets get demoted to reloads), float2 staging + interior fast path, XCD-bijective
// swizzle, pk2 pack, bias via MFMA C-in, XOR swizzle (row&7)<<4.

#define CC 64
#define LL 16384
#define NBATCH 32
#define TL 128
#define NTILE 128     // LL/TL
#define XROWS 146     // x pos range [t*TL-2, t*TL+143]
#define PITCH 128     // bytes per LDS row (64 bf16)

typedef short short8 __attribute__((ext_vector_type(8)));
typedef float f32x4 __attribute__((ext_vector_type(4)));

__device__ __forceinline__ unsigned pk2(float a, float b) {
    unsigned short lo = __builtin_bit_cast(unsigned short, __float2bfloat16(a));
    unsigned short hi = __builtin_bit_cast(unsigned short, __float2bfloat16(b));
    return (unsigned)lo | ((unsigned)hi << 16);
}

// ---- weight repack: w1[64][64][3] f32 -> wp[k][co][ci] bf16 (12288)
//      w2[4][64][3]  f32 -> wp+12288 [k][oc16][ci] bf16 (3072), oc>=4 zero
__global__ void repack_weights(const float* __restrict__ w1,
                               const float* __restrict__ w2,
                               unsigned short* __restrict__ wp) {
    int i = blockIdx.x * 256 + threadIdx.x;
    if (i < 12288) {
        int kk = i >> 12;
        int rem = i & 4095;
        int co = rem >> 6;
        int ci = rem & 63;
        wp[i] = __builtin_bit_cast(unsigned short, __float2bfloat16(w1[(co * 64 + ci) * 3 + kk]));
    }
    if (i < 3072) {
        int kk = i >> 10;
        int rem = i & 1023;
        int oc = rem >> 6;
        int ci = rem & 63;
        float v = (oc < 4) ? w2[(oc * 64 + ci) * 3 + kk] : 0.0f;
        wp[12288 + i] = __builtin_bit_cast(unsigned short, __float2bfloat16(v));
    }
}

__global__ __launch_bounds__(256, 4)
void fused_upsample_mfma(const float* __restrict__ x,
                         const float* __restrict__ b1,
                         const float* __restrict__ b2,
                         const unsigned short* __restrict__ wp,
                         float* __restrict__ out) {
    __shared__ __align__(16) char lds[(XROWS + 2 + 144) * PITCH];
    char* const xs = lds;                         // rows 0..145 : x pos t*TL-2+row
    char* const hs = lds + (XROWS + 2) * PITCH;   // rows 0..143 : h pos t*TL-1+row

    // bijective XCD swizzle: 4096 blocks = 8 XCDs x 512; XCD k gets batches 4k..4k+3
    const int bid = blockIdx.x;
    const int swz = (bid & 7) * 512 + (bid >> 3);
    const int t   = swz & (NTILE - 1);
    const int bb  = swz >> 7;

    const int tid  = threadIdx.x;
    const int lane = tid & 63;
    const int wave = tid >> 6;
    const int lr   = lane & 15;   // fragment row/col index
    const int lg   = lane >> 4;   // k-chunk group 0..3

    // ---------------- stage x -> xs (float2 loads, interior fast path) ----------------
    {
        const int sc  = tid & 15;          // row-pair group: rows {it*32+2sc, +1}
        const int scg = tid >> 4;          // ci-group 0..15
        const long base0 = (long)(bb * CC + scg * 4) * LL;
        const int g0 = t * TL - 2;
        const bool interior = (t > 0) && (t < NTILE - 1);

        if (interior) {
            #pragma unroll
            for (int it = 0; it < 5; ++it) {
                int r = it * 32 + sc * 2;
                if (it < 4 || r < XROWS) {
                    float2 v0 = *(const float2*)(x + base0 + g0 + r);
                    float2 v1 = *(const float2*)(x + base0 + LL + g0 + r);
                    float2 v2 = *(const float2*)(x + base0 + 2 * LL + g0 + r);
                    float2 v3 = *(const float2*)(x + base0 + 3 * LL + g0 + r);
                    int byteA = (r * PITCH + scg * 8) ^ ((r & 7) << 4);
                    int byteB = ((r + 1) * PITCH + scg * 8) ^ (((r + 1) & 7) << 4);
                    *(uint2*)(xs + byteA) = make_uint2(pk2(v0.x, v1.x), pk2(v2.x, v3.x));
                    *(uint2*)(xs + byteB) = make_uint2(pk2(v0.y, v1.y), pk2(v2.y, v3.y));
                }
            }
        } else {
            #pragma unroll
            for (int it = 0; it < 5; ++it) {
                int r = it * 32 + sc * 2;
                if (it < 4 || r < XROWS) {
                    int ga = g0 + r, gb = g0 + r + 1;
                    bool oa = (unsigned)ga < (unsigned)LL;
                    bool ob = (unsigned)gb < (unsigned)LL;
                    float2 v[4];
                    #pragma unroll
                    for (int u = 0; u < 4; ++u) {
                        v[u].x = oa ? x[base0 + (long)u * LL + ga] : 0.f;
                        v[u].y = ob ? x[base0 + (long)u * LL + gb] : 0.f;
                    }
                    int byteA = (r * PITCH + scg * 8) ^ ((r & 7) << 4);
                    int byteB = ((r + 1) * PITCH + scg * 8) ^ (((r + 1) & 7) << 4);
                    *(uint2*)(xs + byteA) = make_uint2(pk2(v[0].x, v[1].x), pk2(v[2].x, v[3].x));
                    *(uint2*)(xs + byteB) = make_uint2(pk2(v[0].y, v[1].y), pk2(v[2].y, v[3].y));
                }
            }
        }
    }
    __syncthreads();

    // ---------------- conv1: wave owns co-tile `wave`, loops all 9 pos-tiles ----------------
    {
        short8 A1[3][2];
        #pragma unroll
        for (int k = 0; k < 3; ++k)
            #pragma unroll
            for (int kc = 0; kc < 2; ++kc)
                A1[k][kc] = *(const short8*)(wp + ((k * 64 + wave * 16 + lr) * 64 + kc * 32 + lg * 8));
        const f32x4 bias1 = *(const f32x4*)(b1 + wave * 16 + lg * 4);

        #pragma unroll 3
        for (int i = 0; i < 9; ++i) {
            f32x4 acc = bias1;
            #pragma unroll
            for (int k = 0; k < 3; ++k) {
                int row = 16 * i + lr + k;             // xs row = p + k + 1
                #pragma unroll
                for (int kc = 0; kc < 2; ++kc) {
                    int byte = (row * PITCH + kc * 64 + lg * 16) ^ ((row & 7) << 4);
                    short8 Bf = *(const short8*)(xs + byte);
                    acc = __builtin_amdgcn_mfma_f32_16x16x32_bf16(A1[k][kc], Bf, acc, 0, 0, 0);
                }
            }
            int p  = 16 * i - 1 + lr;                  // local h pos
            int hp = t * TL + p;                       // global h pos
            bool inr = (unsigned)hp < (unsigned)LL;
            float r0 = inr ? fmaxf(acc[0], 0.f) : 0.f;
            float r1 = inr ? fmaxf(acc[1], 0.f) : 0.f;
            float r2 = inr ? fmaxf(acc[2], 0.f) : 0.f;
            float r3 = inr ? fmaxf(acc[3], 0.f) : 0.f;
            int hrow = 16 * i + lr;                    // hs row = p + 1
            int byte = (hrow * PITCH + wave * 32 + lg * 8) ^ ((hrow & 7) << 4);
            *(uint2*)(hs + byte) = make_uint2(pk2(r0, r1), pk2(r2, r3));
        }
    }
    __syncthreads();

    // ---------------- conv2 + pixelshuffle store: wave does 2 pos-tiles ----------------
    {
        short8 A2[3][2];
        #pragma unroll
        for (int k = 0; k < 3; ++k)
            #pragma unroll
            for (int kc = 0; kc < 2; ++kc)
                A2[k][kc] = *(const short8*)(wp + 12288 + ((k * 16 + lr) * 64 + kc * 32 + lg * 8));
        const f32x4 bias2v = *(const f32x4*)(b2);
        const f32x4 zero4 = {0.f, 0.f, 0.f, 0.f};
        const f32x4 acc2init = (lg == 0) ? bias2v : zero4;

        #pragma unroll
        for (int s = 0; s < 2; ++s) {
            int p0 = 16 * (wave * 2 + s);
            f32x4 acc = acc2init;
            #pragma unroll
            for (int k = 0; k < 3; ++k) {
                int row = p0 + lr + k;                 // hs row = p + k
                #pragma unroll
                for (int kc = 0; kc < 2; ++kc) {
                    int byte = (row * PITCH + kc * 64 + lg * 16) ^ ((row & 7) << 4);
                    short8 Bf = *(const short8*)(hs + byte);
                    acc = __builtin_amdgcn_mfma_f32_16x16x32_bf16(A2[k][kc], Bf, acc, 0, 0, 0);
                }
            }
            if (lane < 16) {                           // lg=0: regs 0..3 = oc 0..3
                f32x4 o;
                o[0] = fmaxf(acc[0], 0.f);
                o[1] = fmaxf(acc[1], 0.f);
                o[2] = fmaxf(acc[2], 0.f);
                o[3] = fmaxf(acc[3], 0.f);
                *(f32x4*)(out + (long)bb * (LL * 4) + (t * TL + p0 + lane) * 4) = o;
            }
        }
    }
}

extern "C" void kernel_launch(void* const* d_in, const int* in_sizes, int n_in,
                              void* d_out, int out_size, void* d_ws, size_t ws_size,
                              hipStream_t stream) {
    const float* x  = (const float*)d_in[0];
    const float* w1 = (const float*)d_in[1];
    const float* b1 = (const float*)d_in[2];
    const float* w2 = (const float*)d_in[3];
    const float* b2 = (const float*)d_in[4];
    float* out = (float*)d_out;
    unsigned short* wp = (unsigned short*)d_ws;

    repack_weights<<<48, 256, 0, stream>>>(w1, w2, wp);
    fused_upsample_mfma<<<NTILE * NBATCH, 256, 0, stream>>>(x, b1, b2, wp, out);
}